// Round 2
// baseline (587.193 us; speedup 1.0000x reference)
//
#include <hip/hip_runtime.h>
#include <hip/hip_bf16.h>

#define EPSV 1e-5f

typedef __attribute__((ext_vector_type(8))) short bf16x8;
typedef __attribute__((ext_vector_type(4))) float f32x4;

constexpr int NB = 64, CI = 512, HH = 56, WW = 56, CO = 256, PH = 28, PW = 28;
constexpr int PPI = PH * PW;          // 784 pooled pixels per image
constexpr int MTOT = NB * PPI;        // 50176

__device__ __forceinline__ ushort f2bf(float f) {
  union { float f; unsigned u; } v; v.f = f;
  unsigned r = v.u + 0x7FFF + ((v.u >> 16) & 1);   // RNE
  return (ushort)(r >> 16);
}

// --- kernel 0: conv_w fp32 -> bf16 -------------------------------------------
__global__ __launch_bounds__(256) void wconv_kernel(const float* __restrict__ w,
                                                    ushort* __restrict__ wb) {
  int i = (blockIdx.x * 256 + threadIdx.x) * 4;
  float4 v = *reinterpret_cast<const float4*>(w + i);
  ushort4 o;
  o.x = f2bf(v.x); o.y = f2bf(v.y); o.z = f2bf(v.z); o.w = f2bf(v.w);
  *reinterpret_cast<ushort4*>(wb + i) = o;
}

// --- kernel 1: BN + ReLU + 2x2 avgpool, NCHW -> act[m][c] bf16 ---------------
// one block per (n, ph); m = n*784 + ph*28 + pw
__global__ __launch_bounds__(256) void bnpool_kernel(
    const float* __restrict__ x, const float* __restrict__ bw,
    const float* __restrict__ bb, const float* __restrict__ bmean,
    const float* __restrict__ bvar, ushort* __restrict__ act) {
  __shared__ float2 ss[CI];          // (scale, shift) per channel
  __shared__ ushort pl[PW][CI];      // pooled tile, col XOR-swizzled by pw<<2

  const int bid = blockIdx.x;        // n*28 + ph
  const int n = bid / PH, ph = bid - n * PH;
  const int tid = threadIdx.x;

  for (int c = tid; c < CI; c += 256) {
    float sc = bw[c] * rsqrtf(bvar[c] + EPSV);
    ss[c] = make_float2(sc, bb[c] - bmean[c] * sc);
  }
  __syncthreads();

  const int pw = tid & 31;           // 28 active, 4 idle per 32
  const int cl = tid >> 5;           // 8 channel-lanes
  if (pw < PW) {
    const float* xp = x + (((size_t)(n * CI + cl) * HH + 2 * ph) * WW + 2 * pw);
    const size_t cstep = (size_t)8 * HH * WW;
#pragma unroll 4
    for (int it = 0; it < 64; ++it) {
      const int c = it * 8 + cl;
      float2 a = *reinterpret_cast<const float2*>(xp);
      float2 b = *reinterpret_cast<const float2*>(xp + WW);
      float2 s = ss[c];
      float v0 = fmaxf(fmaf(a.x, s.x, s.y), 0.f);
      float v1 = fmaxf(fmaf(a.y, s.x, s.y), 0.f);
      float v2 = fmaxf(fmaf(b.x, s.x, s.y), 0.f);
      float v3 = fmaxf(fmaf(b.y, s.x, s.y), 0.f);
      pl[pw][c ^ (pw << 2)] = f2bf((v0 + v1 + v2 + v3) * 0.25f);
      xp += cstep;
    }
  }
  __syncthreads();

  // write act[m][c], K-contiguous, ushort4 coalesced
  const size_t mbase = (size_t)bid * PW;
  for (int j = tid; j < PW * (CI / 4); j += 256) {   // 14 iters exact
    const int pw2 = j >> 7;
    const int c4 = (j & 127) << 2;
    const int col = c4 ^ (pw2 << 2);
    ushort4 v = *reinterpret_cast<const ushort4*>(&pl[pw2][col]);
    *reinterpret_cast<ushort4*>(act + (mbase + pw2) * CI + c4) = v;
  }
}

// --- kernel 2: C[o][m] = sum_k Wb[o][k] * act[m][k], out NCHW ----------------
// 128(o) x 128(m) tile, BK=32, 4 waves of 64x64, global_load_lds staging
__global__ __launch_bounds__(256) void gemm_kernel(
    const ushort* __restrict__ Wb, const ushort* __restrict__ act,
    float* __restrict__ out) {
  __shared__ ushort lA[128 * 32];    // W tile  [o][k]
  __shared__ ushort lB[128 * 32];    // act tile [m][k]

  const int tid = threadIdx.x;
  const int bid = blockIdx.x;
  const int o0 = (bid & 1) * 128;
  const int m0 = (bid >> 1) * 128;
  const int lane = tid & 63, wid = tid >> 6;
  const int l15 = lane & 15, l4 = lane >> 4;

  // staging: 512 x 16B chunks per tile; 2 chunks per wave-call, 2 calls/wave
  const int ch0 = wid * 128 + lane;
  const int ch1 = ch0 + 64;
  const ushort* gA0 = Wb + (size_t)(o0 + (ch0 >> 2)) * CI + (ch0 & 3) * 8;
  const ushort* gA1 = Wb + (size_t)(o0 + (ch1 >> 2)) * CI + (ch1 & 3) * 8;
  const ushort* gB0 = act + (size_t)(m0 + (ch0 >> 2)) * CI + (ch0 & 3) * 8;
  const ushort* gB1 = act + (size_t)(m0 + (ch1 >> 2)) * CI + (ch1 & 3) * 8;
  ushort* lA0 = lA + wid * 1024;
  ushort* lA1 = lA0 + 512;
  ushort* lB0 = lB + wid * 1024;
  ushort* lB1 = lB0 + 512;

  f32x4 acc[4][4] = {};
  const int wo = (wid >> 1) * 64, wm = (wid & 1) * 64;

  for (int k0 = 0; k0 < CI; k0 += 32) {
    __syncthreads();   // previous compute done before overwrite
    __builtin_amdgcn_global_load_lds((const __attribute__((address_space(1))) void*)(gA0 + k0),
                                     (__attribute__((address_space(3))) void*)lA0, 16, 0, 0);
    __builtin_amdgcn_global_load_lds((const __attribute__((address_space(1))) void*)(gA1 + k0),
                                     (__attribute__((address_space(3))) void*)lA1, 16, 0, 0);
    __builtin_amdgcn_global_load_lds((const __attribute__((address_space(1))) void*)(gB0 + k0),
                                     (__attribute__((address_space(3))) void*)lB0, 16, 0, 0);
    __builtin_amdgcn_global_load_lds((const __attribute__((address_space(1))) void*)(gB1 + k0),
                                     (__attribute__((address_space(3))) void*)lB1, 16, 0, 0);
    __syncthreads();   // compiler drains vmcnt before barrier -> LDS ready

    bf16x8 aF[4], bF[4];
#pragma unroll
    for (int i = 0; i < 4; ++i) {
      aF[i] = *reinterpret_cast<const bf16x8*>(&lA[(wo + i * 16 + l15) * 32 + l4 * 8]);
      bF[i] = *reinterpret_cast<const bf16x8*>(&lB[(wm + i * 16 + l15) * 32 + l4 * 8]);
    }
#pragma unroll
    for (int io = 0; io < 4; ++io)
#pragma unroll
      for (int im = 0; im < 4; ++im)
        acc[io][im] = __builtin_amdgcn_mfma_f32_16x16x32_bf16(aF[io], bF[im], acc[io][im], 0, 0, 0);
  }

  // epilogue: C/D layout col=lane&15 (m), row=(lane>>4)*4+r (o)
#pragma unroll
  for (int im = 0; im < 4; ++im) {
    const int gm = m0 + wm + im * 16 + l15;
    const int nn = gm / PPI;
    const int p = gm - nn * PPI;
    float* ob = out + (size_t)nn * CO * PPI + p;
#pragma unroll
    for (int io = 0; io < 4; ++io) {
      const int obase = o0 + wo + io * 16 + l4 * 4;
#pragma unroll
      for (int r = 0; r < 4; ++r)
        ob[(size_t)(obase + r) * PPI] = acc[io][im][r];
    }
  }
}

extern "C" void kernel_launch(void* const* d_in, const int* in_sizes, int n_in,
                              void* d_out, int out_size, void* d_ws, size_t ws_size,
                              hipStream_t stream) {
  const float* x     = (const float*)d_in[0];
  const float* bw    = (const float*)d_in[1];
  const float* bb    = (const float*)d_in[2];
  const float* bmean = (const float*)d_in[3];
  const float* bvar  = (const float*)d_in[4];
  const float* cw    = (const float*)d_in[5];

  ushort* act = (ushort*)d_ws;                                  // 50176*512*2 B
  ushort* wb  = (ushort*)((char*)d_ws + (size_t)MTOT * CI * 2); // 256*512*2 B

  wconv_kernel<<<dim3((CO * CI) / (256 * 4)), 256, 0, stream>>>(cw, wb);
  bnpool_kernel<<<dim3(NB * PH), 256, 0, stream>>>(x, bw, bb, bmean, bvar, act);
  gemm_kernel<<<dim3((MTOT / 128) * 2), 256, 0, stream>>>(wb, act, (float*)d_out);
}